// Round 13
// baseline (143.492 us; speedup 1.0000x reference)
//
#include <hip/hip_runtime.h>
#include <hip/hip_bf16.h>

typedef __attribute__((ext_vector_type(2))) unsigned int u32x2;
typedef __attribute__((ext_vector_type(4))) float f32x4;
typedef __attribute__((ext_vector_type(4))) unsigned int u32x4;
typedef __attribute__((ext_vector_type(8))) short s16x8;

#define B_  128
#define P_  196
#define E_  2048
#define D_  512
#define A_  512
#define M_  (B_*P_)   // 25088

// global_load_lds: 16B per lane, dest = wave-uniform base + lane*16
typedef __attribute__((address_space(1))) const unsigned int gu32;
typedef __attribute__((address_space(3))) unsigned int lu32;
__device__ __forceinline__ void gl_lds16(const void* g, void* l) {
  __builtin_amdgcn_global_load_lds((gu32*)g, (lu32*)l, 16, 0, 0);
}

#define WAIT_VM6() asm volatile("s_waitcnt vmcnt(6)" ::: "memory")
#define WAIT_VM5() asm volatile("s_waitcnt vmcnt(5)" ::: "memory")
#define WAIT_VM4() asm volatile("s_waitcnt vmcnt(4)" ::: "memory")
#define WAIT_VM0() asm volatile("s_waitcnt vmcnt(0)" ::: "memory")
#define WAIT_LGKM0() asm volatile("s_waitcnt lgkmcnt(0)" ::: "memory")

// ---------------------------------------------------------------------------
// Kernel W: transpose + rne-bf16 + PRE-SWIZZLED TILED store:
// WeTs[kt*16384 + ((a*32 + c8*8) ^ ((a&7)<<3)) + j] == exact 32KB LDS image
// of K-tile kt (a = n-row 0..511, c8 = (e&31)>>3, j = e&7).
// ---------------------------------------------------------------------------
__global__ void we_conv_kernel(const float* __restrict__ We,
                               unsigned short* __restrict__ WeTs) {
  __shared__ float tile[32][33];
  const int tx = threadIdx.x, ty = threadIdx.y;
  const int a0 = blockIdx.x * 32, e0 = blockIdx.y * 32;
  tile[ty][tx] = We[(e0 + ty) * A_ + a0 + tx];
  __syncthreads();
  const float v = tile[tx][ty];              // = We[e0+tx][a0+ty]
  const unsigned int u = __float_as_uint(v);
  const unsigned short r = (unsigned short)((u + 0x7fffu + ((u >> 16) & 1u)) >> 16);
  const int a = a0 + ty;                     // n-row 0..511
  const int kt = blockIdx.y;                 // e-tile
  const int c8 = tx >> 3, j = tx & 7;
  const int dest = ((a * 32 + c8 * 8) ^ ((a & 7) << 3)) + j;
  WeTs[kt * 16384 + dest] = r;
}

// ---------------------------------------------------------------------------
// Kernel A: att2pb[b][a] = decoder_hidden[b] @ Wd + bd[a] + be[a]  (fp32)
// ---------------------------------------------------------------------------
__global__ void att2_kernel(const float* __restrict__ h, const float* __restrict__ Wd,
                            const float* __restrict__ bd, const float* __restrict__ be,
                            float* __restrict__ att2pb) {
  const int b = blockIdx.x;
  const int t = threadIdx.x;  // 256
  __shared__ float hs[D_];
  hs[t] = h[b * D_ + t];
  hs[t + 256] = h[b * D_ + t + 256];
  __syncthreads();
  float a0 = 0.f, a1 = 0.f;
  for (int d = 0; d < D_; ++d) {
    const float hv = hs[d];
    a0 = fmaf(hv, Wd[d * A_ + t], a0);
    a1 = fmaf(hv, Wd[d * A_ + t + 256], a1);
  }
  att2pb[b * A_ + t] = a0 + bd[t] + be[t];
  att2pb[b * A_ + t + 256] = a1 + bd[t + 256] + be[t + 256];
}

// ---------------------------------------------------------------------------
__device__ inline unsigned pk2(float a, float b) {
  union { __hip_bfloat162 h; unsigned u; } cv;
  cv.h = __float22bfloat162_rn(make_float2(a, b));
  return cv.u;
}
__device__ __forceinline__ s16x8 ldsr(const unsigned short* p) {
  return *(const s16x8*)p;
}

// ---------------------------------------------------------------------------
// Kernel B v12: R11 geometry (128m x 512n, 16 waves, wave tile 64x64 = 2m x 8n,
// B depth-4 ring + A depth-2 ring, counted vmcnt + raw barrier) with the
// compute FULLY HAND-UNROLLED (constant indices only — no macro-unroll risk;
// R11's VGPR=64 showed acc spilled to scratch via failed unroll).
// ---------------------------------------------------------------------------
#define MF(a, b, c) c = __builtin_amdgcn_mfma_f32_16x16x32_bf16(a, b, c, 0, 0, 0)

#define COMPUTE_TILE(AB, BB) do {                                              \
    const s16x8 A0 = ldsr((AB) + fa[0]);                                       \
    const s16x8 A1 = ldsr((AB) + fa[1]);                                       \
    const s16x8 A2 = ldsr((AB) + fa[2]);                                       \
    const s16x8 A3 = ldsr((AB) + fa[3]);                                       \
    s16x8 Bf0 = ldsr((BB) + fb[0]);                                            \
    s16x8 Bf1 = ldsr((BB) + fb[1]);                                            \
    __builtin_amdgcn_s_setprio(1);                                             \
    MF(A0, Bf0, acc[0][0]); MF(A1, Bf0, acc[1][0]);                            \
    MF(A2, Bf0, acc[2][0]); MF(A3, Bf0, acc[3][0]);                            \
    MF(A0, Bf1, acc[0][1]); MF(A1, Bf1, acc[1][1]);                            \
    MF(A2, Bf1, acc[2][1]); MF(A3, Bf1, acc[3][1]);                            \
    __builtin_amdgcn_s_setprio(0);                                             \
    Bf0 = ldsr((BB) + fb[2]);                                                  \
    Bf1 = ldsr((BB) + fb[3]);                                                  \
    __builtin_amdgcn_s_setprio(1);                                             \
    MF(A0, Bf0, acc[0][2]); MF(A1, Bf0, acc[1][2]);                            \
    MF(A2, Bf0, acc[2][2]); MF(A3, Bf0, acc[3][2]);                            \
    MF(A0, Bf1, acc[0][3]); MF(A1, Bf1, acc[1][3]);                            \
    MF(A2, Bf1, acc[2][3]); MF(A3, Bf1, acc[3][3]);                            \
    __builtin_amdgcn_s_setprio(0);                                             \
  } while (0)

__launch_bounds__(1024, 4)
__global__ void score_kernel(const float* __restrict__ enc,
                             const unsigned short* __restrict__ WeTs,
                             const float* __restrict__ att2pb,
                             const float* __restrict__ Wf,
                             float* __restrict__ att_part) {
  __shared__ unsigned short Bh[4][512 * 32];   // 4 x 32 KB, swizzled image
  __shared__ unsigned short Ahs[2][128 * 32];  // 2 x  8 KB, swizzled image

  const int bid = blockIdx.x;               // 0..195
  const int m0 = bid * 128;

  const int t = threadIdx.x;                // 0..1023
  const int lane = t & 63, w = t >> 6;      // 16 waves
  const int wm = (w >> 3) * 64;             // 0 | 64
  const int wn = (w & 7) * 64;              // 0..448

  // A staging: row ar = t>>3 (0..127), 4 f32 at chunk ac4 = t&7 -> 8B write
  const int ar = t >> 3, ac4 = t & 7;
  const float* aptr = enc + (size_t)(m0 + ar) * E_ + ac4 * 4;
  const int awz = (ar * 32 + ac4 * 4) ^ ((ar & 7) << 3);

  // B DMA: 2 x 16B per thread (linear image copy); chunk i at +i*8192 shorts
  const int doff = t * 8;

  // fragment read offsets
  const int q = lane >> 4, fr = lane & 15;
  const int fx = (fr & 7) << 3;
  int fa[4], fb[4];
#pragma unroll
  for (int i = 0; i < 4; ++i) {
    fa[i] = ((wm + i * 16 + fr) * 32 + q * 8) ^ fx;
    fb[i] = ((wn + i * 16 + fr) * 32 + q * 8) ^ fx;
  }

  const f32x4 zero = {0.f, 0.f, 0.f, 0.f};
  f32x4 acc[4][4];
#pragma unroll
  for (int mi = 0; mi < 4; ++mi)
#pragma unroll
    for (int ni = 0; ni < 4; ++ni) acc[mi][ni] = zero;

  f32x4 aC, aN;   // A regs: aC = tile t+1 (cvt at end of iter t), aN = t+2

  // ---- prologue: issues [A0, B0x2, A1, B1x2, B2x2]
  {
    aC = *(const f32x4*)(aptr);                               // A(0)
    gl_lds16(WeTs + doff, &Bh[0][doff]);                      // B(0)
    gl_lds16(WeTs + 8192 + doff, &Bh[0][8192 + doff]);
    aN = *(const f32x4*)(aptr + 32);                          // A(1)
    gl_lds16(WeTs + 16384 + doff, &Bh[1][doff]);              // B(1)
    gl_lds16(WeTs + 16384 + 8192 + doff, &Bh[1][8192 + doff]);
    gl_lds16(WeTs + 32768 + doff, &Bh[2][doff]);              // B(2)
    gl_lds16(WeTs + 32768 + 8192 + doff, &Bh[2][8192 + doff]);
    u32x2 av; av[0] = pk2(aC[0], aC[1]); av[1] = pk2(aC[2], aC[3]);
    *(u32x2*)(&Ahs[0][awz]) = av;                             // A(0) -> LDS
    aC = aN;
    WAIT_VM5();     // retires B(0) (newest 5 = A1, B1x2, B2x2)
    WAIT_LGKM0();
    __builtin_amdgcn_s_barrier();
  }

  for (int it = 0; it < 61; ++it) {
    // 1) issue A(t+2) load + B(t+3) DMAs  (issue order [A,B,B])
    const int kof = (it + 2) * 32;
    aN = *(const f32x4*)(aptr + kof);
    {
      const unsigned short* sb = WeTs + (size_t)(it + 3) * 16384;
      unsigned short* bt = &Bh[(it + 3) & 3][0];
      gl_lds16(sb + doff, bt + doff);
      gl_lds16(sb + 8192 + doff, bt + 8192 + doff);
    }

    // 2) compute tile t
    COMPUTE_TILE(&Ahs[it & 1][0], &Bh[it & 3][0]);

    // 3) cvt + write A(t+1)  (aC regs retired long ago; compiler-counted wait)
    {
      u32x2 av; av[0] = pk2(aC[0], aC[1]); av[1] = pk2(aC[2], aC[3]);
      *(u32x2*)(&Ahs[(it + 1) & 1][awz]) = av;
    }
    aC = aN;

    // 4) counted drain: B(t+1)+A(t+1) resident after this (newest 6 may fly)
    WAIT_VM6();
    WAIT_LGKM0();
    __builtin_amdgcn_s_barrier();
  }

  // ---- it = 61: issue A(63) only; compute 61; write A(62); need B(62)
  {
    aN = *(const f32x4*)(aptr + 63 * 32);
    COMPUTE_TILE(&Ahs[1][0], &Bh[1][0]);
    u32x2 av; av[0] = pk2(aC[0], aC[1]); av[1] = pk2(aC[2], aC[3]);
    *(u32x2*)(&Ahs[0][awz]) = av;
    aC = aN;
    WAIT_VM4();     // retires B(62) (newest 4 = A62, B63x2, A63)
    WAIT_LGKM0();
    __builtin_amdgcn_s_barrier();
  }

  // ---- it = 62: compute 62; write A(63); need B(63)
  {
    COMPUTE_TILE(&Ahs[0][0], &Bh[2][0]);
    u32x2 av; av[0] = pk2(aC[0], aC[1]); av[1] = pk2(aC[2], aC[3]);
    *(u32x2*)(&Ahs[1][awz]) = av;
    WAIT_VM0();
    WAIT_LGKM0();
    __builtin_amdgcn_s_barrier();
  }

  // ---- it = 63: final tile
  COMPUTE_TILE(&Ahs[1][0], &Bh[3][0]);

  // epilogue: s = sum_col relu(acc + att2pb[b][col]) * Wf[col], 16-lane reduce
  // C/D layout: col = lane&15, row = (lane>>4)*4 + reg
  const int colL = wn + fr;
  float wfv[4];
#pragma unroll
  for (int ni = 0; ni < 4; ++ni) wfv[ni] = Wf[colL + ni * 16];
#pragma unroll
  for (int mi = 0; mi < 4; ++mi) {
    const int rowb = m0 + wm + mi * 16 + (q << 2);
#pragma unroll
    for (int r = 0; r < 4; ++r) {
      const int row = rowb + r;
      const int bb = row / P_;
      const float* a2 = att2pb + bb * A_ + colL;
      float s = 0.f;
#pragma unroll
      for (int ni = 0; ni < 4; ++ni)
        s += fmaxf(acc[mi][ni][r] + a2[ni * 16], 0.f) * wfv[ni];
#pragma unroll
      for (int off = 1; off < 16; off <<= 1) s += __shfl_xor(s, off);
      if (fr == 0) att_part[row * 8 + (w & 7)] = s;
    }
  }
}

// ---------------------------------------------------------------------------
// Kernel C: per (b, e-chunk): sum 8 partials -> softmax over P -> alpha,
// awe[b][e] = sum_p alpha[p] * enc[b][p][e].  grid = B*2, block 256.
// ---------------------------------------------------------------------------
__global__ void softmax_awe_kernel(const float* __restrict__ enc,
                                   const float* __restrict__ att_part,
                                   float* __restrict__ out) {
  const int bid = blockIdx.x;
  const int b = bid >> 1, ch = bid & 1;
  const int t = threadIdx.x;
  __shared__ float sm[256];
  __shared__ float alpha_s[P_];

  float av = -1e30f;
  if (t < P_) {
    const float* apt = att_part + (b * P_ + t) * 8;
    float s = 0.f;
#pragma unroll
    for (int i = 0; i < 8; ++i) s += apt[i];
    av = s;
  }
  sm[t] = av;
  __syncthreads();
  for (int st = 128; st > 0; st >>= 1) {
    if (t < st) sm[t] = fmaxf(sm[t], sm[t + st]);
    __syncthreads();
  }
  const float mx = sm[0];
  __syncthreads();
  float ev = 0.f;
  if (t < P_) ev = __expf(av - mx);
  sm[t] = ev;
  __syncthreads();
  for (int st = 128; st > 0; st >>= 1) {
    if (t < st) sm[t] += sm[t + st];
    __syncthreads();
  }
  const float denom = sm[0];
  const float al = ev / denom;
  if (t < P_) {
    alpha_s[t] = al;
    if (ch == 0) out[B_ * E_ + b * P_ + t] = al;   // alpha output
  }
  __syncthreads();

  const int e0 = ch * 1024 + t * 4;
  const float* ebase = enc + (size_t)b * P_ * E_ + e0;
  f32x4 acc = {0.f, 0.f, 0.f, 0.f};
  for (int p = 0; p < P_; ++p) {
    const f32x4 v = *(const f32x4*)(ebase + (size_t)p * E_);
    const float a = alpha_s[p];
    acc.x += a * v.x; acc.y += a * v.y; acc.z += a * v.z; acc.w += a * v.w;
  }
  *(f32x4*)(out + b * E_ + e0) = acc;
}

// ---------------------------------------------------------------------------
extern "C" void kernel_launch(void* const* d_in, const int* in_sizes, int n_in,
                              void* d_out, int out_size, void* d_ws, size_t ws_size,
                              hipStream_t stream) {
  const float* enc = (const float*)d_in[0];
  const float* h   = (const float*)d_in[1];
  const float* We  = (const float*)d_in[2];
  const float* be  = (const float*)d_in[3];
  const float* Wd  = (const float*)d_in[4];
  const float* bd  = (const float*)d_in[5];
  const float* Wf  = (const float*)d_in[6];
  // d_in[7] = bf: constant shift before softmax -> cancels; unused.
  float* out = (float*)d_out;

  // workspace layout (~3.1 MB)
  float* att2pb = (float*)d_ws;                       // 128*512 f32
  float* att_part = att2pb + B_ * A_;                 // 25088*8 f32
  unsigned short* WeTs = (unsigned short*)(att_part + M_ * 8);  // 64*16384 u16

  we_conv_kernel<<<dim3(A_ / 32, E_ / 32), dim3(32, 32), 0, stream>>>(We, WeTs);
  att2_kernel<<<B_, 256, 0, stream>>>(h, Wd, bd, be, att2pb);
  score_kernel<<<M_ / 128, 1024, 0, stream>>>(enc, WeTs, att2pb, Wf, att_part);
  softmax_awe_kernel<<<B_ * 2, 256, 0, stream>>>(enc, att_part, out);
}

// Round 14
// 142.856 us; speedup vs baseline: 1.0045x; 1.0045x over previous
//
#include <hip/hip_runtime.h>
#include <hip/hip_bf16.h>

typedef __attribute__((ext_vector_type(2))) unsigned int u32x2;
typedef __attribute__((ext_vector_type(4))) float f32x4;
typedef __attribute__((ext_vector_type(4))) unsigned int u32x4;
typedef __attribute__((ext_vector_type(8))) short s16x8;

#define B_  128
#define P_  196
#define E_  2048
#define D_  512
#define A_  512
#define M_  (B_*P_)   // 25088

// global_load_lds: 16B per lane, dest = wave-uniform base + lane*16
typedef __attribute__((address_space(1))) const unsigned int gu32;
typedef __attribute__((address_space(3))) unsigned int lu32;
__device__ __forceinline__ void gl_lds16(const void* g, void* l) {
  __builtin_amdgcn_global_load_lds((gu32*)g, (lu32*)l, 16, 0, 0);
}

#define WAIT_VM3() asm volatile("s_waitcnt vmcnt(3)" ::: "memory")
#define WAIT_VM0() asm volatile("s_waitcnt vmcnt(0)" ::: "memory")
#define WAIT_LGKM0() asm volatile("s_waitcnt lgkmcnt(0)" ::: "memory")

// ---------------------------------------------------------------------------
// Kernel W: transpose + rne-bf16 + PRE-SWIZZLED TILED store:
// WeTs[kt*16384 + ((a*32 + c8*8) ^ ((a&7)<<3)) + j] == exact 32KB LDS image
// of K-tile kt (a = n-row 0..511, c8 = (e&31)>>3, j = e&7).
// ---------------------------------------------------------------------------
__global__ void we_conv_kernel(const float* __restrict__ We,
                               unsigned short* __restrict__ WeTs) {
  __shared__ float tile[32][33];
  const int tx = threadIdx.x, ty = threadIdx.y;
  const int a0 = blockIdx.x * 32, e0 = blockIdx.y * 32;
  tile[ty][tx] = We[(e0 + ty) * A_ + a0 + tx];
  __syncthreads();
  const float v = tile[tx][ty];              // = We[e0+tx][a0+ty]
  const unsigned int u = __float_as_uint(v);
  const unsigned short r = (unsigned short)((u + 0x7fffu + ((u >> 16) & 1u)) >> 16);
  const int a = a0 + ty;                     // n-row 0..511
  const int kt = blockIdx.y;                 // e-tile
  const int c8 = tx >> 3, j = tx & 7;
  const int dest = ((a * 32 + c8 * 8) ^ ((a & 7) << 3)) + j;
  WeTs[kt * 16384 + dest] = r;
}

// ---------------------------------------------------------------------------
// Kernel A: att2pb[b][a] = decoder_hidden[b] @ Wd + bd[a] + be[a]  (fp32)
// ---------------------------------------------------------------------------
__global__ void att2_kernel(const float* __restrict__ h, const float* __restrict__ Wd,
                            const float* __restrict__ bd, const float* __restrict__ be,
                            float* __restrict__ att2pb) {
  const int b = blockIdx.x;
  const int t = threadIdx.x;  // 256
  __shared__ float hs[D_];
  hs[t] = h[b * D_ + t];
  hs[t + 256] = h[b * D_ + t + 256];
  __syncthreads();
  float a0 = 0.f, a1 = 0.f;
  for (int d = 0; d < D_; ++d) {
    const float hv = hs[d];
    a0 = fmaf(hv, Wd[d * A_ + t], a0);
    a1 = fmaf(hv, Wd[d * A_ + t + 256], a1);
  }
  att2pb[b * A_ + t] = a0 + bd[t] + be[t];
  att2pb[b * A_ + t + 256] = a1 + bd[t + 256] + be[t + 256];
}

// ---------------------------------------------------------------------------
__device__ inline unsigned pk2(float a, float b) {
  union { __hip_bfloat162 h; unsigned u; } cv;
  cv.h = __float22bfloat162_rn(make_float2(a, b));
  return cv.u;
}

// ---------------------------------------------------------------------------
// Kernel B v13 == v10 (proven best, 130.2 total) + early A-write:
// 16 waves (1024 thr), wave tile 32x128 (4m x 4n), K=32, B ring-3 via gl_lds
// DMA (pre-swizzled 32KB images), A ring-3 via reg+cvt, depth-2 prefetch,
// counted vmcnt(3) + raw s_barrier.  The A(t+1) cvt+ds_write now happens
// BEFORE the MFMA cluster (its source regs retired an iteration ago; its
// target buffer is read by nobody this iteration) so the write drains under
// the MFMAs instead of in the pre-barrier lgkm(0).
// ---------------------------------------------------------------------------
__launch_bounds__(1024, 4)
__global__ void score_kernel(const float* __restrict__ enc,
                             const unsigned short* __restrict__ WeTs,
                             const float* __restrict__ att2pb,
                             const float* __restrict__ Wf,
                             float* __restrict__ att_part) {
  __shared__ unsigned short Bh[3][512 * 32];   // 3 x 32 KB, swizzled image
  __shared__ unsigned short Ahs[3][128 * 32];  // 3 x  8 KB, swizzled image

  const int bid = blockIdx.x;               // 0..195
  const int m0 = bid * 128;

  const int t = threadIdx.x;                // 0..1023
  const int lane = t & 63, w = t >> 6;      // 16 waves
  const int wm = (w >> 2) * 32;             // 0 | 32 | 64 | 96
  const int wn = (w & 3) * 128;             // 0 | 128 | 256 | 384

  // A staging: row r = t>>3 (0..127), 4 f32 at chunk c4 = t&7 -> 8B LDS write
  const int ar = t >> 3, ac4 = t & 7;
  const float* aptr = enc + (size_t)(m0 + ar) * E_ + ac4 * 4;
  const int awz = (ar * 32 + ac4 * 4) ^ ((ar & 7) << 3);   // shorts, 8B-aligned

  // B DMA: 2 x 16B per thread (linear image copy)
  const int doff = t * 8;                   // shorts; chunk i at +i*8192

  // fragment read offsets
  const int q = lane >> 4, fr = lane & 15;
  const int fx = (fr & 7) << 3;
  int fa[2], fb[8];
#pragma unroll
  for (int i = 0; i < 2; ++i) fa[i] = ((wm + i * 16 + fr) * 32 + q * 8) ^ fx;
#pragma unroll
  for (int j = 0; j < 8; ++j) fb[j] = ((wn + j * 16 + fr) * 32 + q * 8) ^ fx;

  const f32x4 zero = {0.f, 0.f, 0.f, 0.f};
  f32x4 acc[2][8];
#pragma unroll
  for (int mi = 0; mi < 2; ++mi)
#pragma unroll
    for (int ni = 0; ni < 8; ++ni) acc[mi][ni] = zero;

  // rotating buffers: *_c = compute (tile t), *_1 = t+1, *_2 = DMA tgt (t+2)
  unsigned short *bAc = &Ahs[0][0], *bA1 = &Ahs[1][0], *bA2 = &Ahs[2][0];
  unsigned short *bBc = &Bh[0][0],  *bB1 = &Bh[1][0],  *bB2 = &Bh[2][0];

  f32x4 aC, aN;   // A regs: aC = tile t+1 (cvt in iter t), aN = t+2

  // ---- prologue: stage tiles 0 and 1 (order: A0, B0 x2, A1, B1 x2)
  {
    aC = *(const f32x4*)(aptr);                           // A(0)
    gl_lds16(WeTs + doff, bBc + doff);                    // B(0)
    gl_lds16(WeTs + 8192 + doff, bBc + 8192 + doff);
    aN = *(const f32x4*)(aptr + 32);                      // A(1)
    gl_lds16(WeTs + 16384 + doff, bB1 + doff);            // B(1)
    gl_lds16(WeTs + 16384 + 8192 + doff, bB1 + 8192 + doff);
    u32x2 av; av[0] = pk2(aC[0], aC[1]); av[1] = pk2(aC[2], aC[3]);
    *(u32x2*)(bAc + awz) = av;                            // A(0) -> LDS
    aC = aN;
    WAIT_VM3();     // retires B(0); leaves A(1)+B(1)x2 in flight
    WAIT_LGKM0();
    __builtin_amdgcn_s_barrier();
  }

  for (int it = 0; it < 62; ++it) {
    // 1) issue stage(t+2): 1 A-load + 2 B-DMAs  (3 VMEM ops this iter)
    const int kof = (it + 2) * 32;
    aN = *(const f32x4*)(aptr + kof);
    const unsigned short* sb = WeTs + (size_t)(it + 2) * 16384;
    gl_lds16(sb + doff, bB2 + doff);
    gl_lds16(sb + 8192 + doff, bB2 + 8192 + doff);

    // 2) EARLY cvt + write A(t+1) into bA1 (src regs retired an iter ago;
    //    bA1 is read by nobody this iteration) — drains under the MFMAs
    {
      u32x2 av; av[0] = pk2(aC[0], aC[1]); av[1] = pk2(aC[2], aC[3]);
      *(u32x2*)(bA1 + awz) = av;
    }
    aC = aN;

    // 3) compute buffer t (B in two halves of 4 frags: register pressure)
    s16x8 fah[2], fbh[4];
    fah[0] = *(const s16x8*)(bAc + fa[0]);
    fah[1] = *(const s16x8*)(bAc + fa[1]);
#pragma unroll
    for (int j = 0; j < 4; ++j) fbh[j] = *(const s16x8*)(bBc + fb[j]);
    __builtin_amdgcn_s_setprio(1);
#pragma unroll
    for (int mi = 0; mi < 2; ++mi)
#pragma unroll
      for (int ni = 0; ni < 4; ++ni)
        acc[mi][ni] = __builtin_amdgcn_mfma_f32_16x16x32_bf16(fah[mi], fbh[ni], acc[mi][ni], 0, 0, 0);
    __builtin_amdgcn_s_setprio(0);
#pragma unroll
    for (int j = 0; j < 4; ++j) fbh[j] = *(const s16x8*)(bBc + fb[4 + j]);
    __builtin_amdgcn_s_setprio(1);
#pragma unroll
    for (int mi = 0; mi < 2; ++mi)
#pragma unroll
      for (int ni = 0; ni < 4; ++ni)
        acc[mi][4 + ni] = __builtin_amdgcn_mfma_f32_16x16x32_bf16(fah[mi], fbh[ni], acc[mi][4 + ni], 0, 0, 0);
    __builtin_amdgcn_s_setprio(0);

    // 4) counted drain: this iter's 3 stay in flight; tile t+1 fully resident
    WAIT_VM3();
    WAIT_LGKM0();
    __builtin_amdgcn_s_barrier();

    // 5) rotate
    unsigned short* tmp;
    tmp = bAc; bAc = bA1; bA1 = bA2; bA2 = tmp;
    tmp = bBc; bBc = bB1; bB1 = bB2; bB2 = tmp;
  }

  // ---- it = 62: write A(63) early, compute tile 62, full drain
  {
    u32x2 av; av[0] = pk2(aC[0], aC[1]); av[1] = pk2(aC[2], aC[3]);
    *(u32x2*)(bA1 + awz) = av;                            // A(63)
    s16x8 fah[2], fbh[4];
    fah[0] = *(const s16x8*)(bAc + fa[0]);
    fah[1] = *(const s16x8*)(bAc + fa[1]);
#pragma unroll
    for (int j = 0; j < 4; ++j) fbh[j] = *(const s16x8*)(bBc + fb[j]);
#pragma unroll
    for (int mi = 0; mi < 2; ++mi)
#pragma unroll
      for (int ni = 0; ni < 4; ++ni)
        acc[mi][ni] = __builtin_amdgcn_mfma_f32_16x16x32_bf16(fah[mi], fbh[ni], acc[mi][ni], 0, 0, 0);
#pragma unroll
    for (int j = 0; j < 4; ++j) fbh[j] = *(const s16x8*)(bBc + fb[4 + j]);
#pragma unroll
    for (int mi = 0; mi < 2; ++mi)
#pragma unroll
      for (int ni = 0; ni < 4; ++ni)
        acc[mi][4 + ni] = __builtin_amdgcn_mfma_f32_16x16x32_bf16(fah[mi], fbh[ni], acc[mi][4 + ni], 0, 0, 0);
    WAIT_VM0();     // B(63) retired
    WAIT_LGKM0();
    __builtin_amdgcn_s_barrier();
  }

  // ---- it = 63: compute tile 63 from bA1/bB1
  {
    s16x8 fah[2], fbh[4];
    fah[0] = *(const s16x8*)(bA1 + fa[0]);
    fah[1] = *(const s16x8*)(bA1 + fa[1]);
#pragma unroll
    for (int j = 0; j < 4; ++j) fbh[j] = *(const s16x8*)(bB1 + fb[j]);
#pragma unroll
    for (int mi = 0; mi < 2; ++mi)
#pragma unroll
      for (int ni = 0; ni < 4; ++ni)
        acc[mi][ni] = __builtin_amdgcn_mfma_f32_16x16x32_bf16(fah[mi], fbh[ni], acc[mi][ni], 0, 0, 0);
#pragma unroll
    for (int j = 0; j < 4; ++j) fbh[j] = *(const s16x8*)(bB1 + fb[4 + j]);
#pragma unroll
    for (int mi = 0; mi < 2; ++mi)
#pragma unroll
      for (int ni = 0; ni < 4; ++ni)
        acc[mi][4 + ni] = __builtin_amdgcn_mfma_f32_16x16x32_bf16(fah[mi], fbh[ni], acc[mi][4 + ni], 0, 0, 0);
  }

  // epilogue: s = sum_col relu(acc + att2pb[b][col]) * Wf[col], 16-lane reduce
  // C/D layout: col = lane&15, row = (lane>>4)*4 + reg
  const int colL = wn + fr;
  float wfv[8];
#pragma unroll
  for (int ni = 0; ni < 8; ++ni) wfv[ni] = Wf[colL + ni * 16];
#pragma unroll
  for (int mi = 0; mi < 2; ++mi) {
    const int rowb = m0 + wm + mi * 16 + (q << 2);
#pragma unroll
    for (int r = 0; r < 4; ++r) {
      const int row = rowb + r;
      const int bb = row / P_;
      const float* a2 = att2pb + bb * A_ + colL;
      float s = 0.f;
#pragma unroll
      for (int ni = 0; ni < 8; ++ni)
        s += fmaxf(acc[mi][ni][r] + a2[ni * 16], 0.f) * wfv[ni];
#pragma unroll
      for (int off = 1; off < 16; off <<= 1) s += __shfl_xor(s, off);
      if (fr == 0) att_part[row * 4 + (w & 3)] = s;
    }
  }
}

// ---------------------------------------------------------------------------
// Kernel C: per (b, e-chunk): sum 4 partials -> softmax over P -> alpha,
// awe[b][e] = sum_p alpha[p] * enc[b][p][e].  grid = B*2, block 256.
// ---------------------------------------------------------------------------
__global__ void softmax_awe_kernel(const float* __restrict__ enc,
                                   const float* __restrict__ att_part,
                                   float* __restrict__ out) {
  const int bid = blockIdx.x;
  const int b = bid >> 1, ch = bid & 1;
  const int t = threadIdx.x;
  __shared__ float sm[256];
  __shared__ float alpha_s[P_];

  float av = -1e30f;
  if (t < P_) {
    const float* apt = att_part + (b * P_ + t) * 4;
    av = (apt[0] + apt[1]) + (apt[2] + apt[3]);
  }
  sm[t] = av;
  __syncthreads();
  for (int st = 128; st > 0; st >>= 1) {
    if (t < st) sm[t] = fmaxf(sm[t], sm[t + st]);
    __syncthreads();
  }
  const float mx = sm[0];
  __syncthreads();
  float ev = 0.f;
  if (t < P_) ev = __expf(av - mx);
  sm[t] = ev;
  __syncthreads();
  for (int st = 128; st > 0; st >>= 1) {
    if (t < st) sm[t] += sm[t + st];
    __syncthreads();
  }
  const float denom = sm[0];
  const float al = ev / denom;
  if (t < P_) {
    alpha_s[t] = al;
    if (ch == 0) out[B_ * E_ + b * P_ + t] = al;   // alpha output
  }
  __syncthreads();

  const int e0 = ch * 1024 + t * 4;
  const float* ebase = enc + (size_t)b * P_ * E_ + e0;
  f32x4 acc = {0.f, 0.f, 0.f, 0.f};
  for (int p = 0; p < P_; ++p) {
    const f32x4 v = *(const f32x4*)(ebase + (size_t)p * E_);
    const float a = alpha_s[p];
    acc.x += a * v.x; acc.y += a * v.y; acc.z += a * v.z; acc.w += a * v.w;
  }
  *(f32x4*)(out + b * E_ + e0) = acc;
}

// ---------------------------------------------------------------------------
extern "C" void kernel_launch(void* const* d_in, const int* in_sizes, int n_in,
                              void* d_out, int out_size, void* d_ws, size_t ws_size,
                              hipStream_t stream) {
  const float* enc = (const float*)d_in[0];
  const float* h   = (const float*)d_in[1];
  const float* We  = (const float*)d_in[2];
  const float* be  = (const float*)d_in[3];
  const float* Wd  = (const float*)d_in[4];
  const float* bd  = (const float*)d_in[5];
  const float* Wf  = (const float*)d_in[6];
  // d_in[7] = bf: constant shift before softmax -> cancels; unused.
  float* out = (float*)d_out;

  // workspace layout (~2.7 MB)
  float* att2pb = (float*)d_ws;                       // 128*512 f32
  float* att_part = att2pb + B_ * A_;                 // 25088*4 f32
  unsigned short* WeTs = (unsigned short*)(att_part + M_ * 4);  // 64*16384 u16

  we_conv_kernel<<<dim3(A_ / 32, E_ / 32), dim3(32, 32), 0, stream>>>(We, WeTs);
  att2_kernel<<<B_, 256, 0, stream>>>(h, Wd, bd, be, att2pb);
  score_kernel<<<M_ / 128, 1024, 0, stream>>>(enc, WeTs, att2pb, Wf, att_part);
  softmax_awe_kernel<<<B_ * 2, 256, 0, stream>>>(enc, att_part, out);
}

// Round 15
// 130.446 us; speedup vs baseline: 1.1000x; 1.0951x over previous
//
#include <hip/hip_runtime.h>
#include <hip/hip_bf16.h>

typedef __attribute__((ext_vector_type(2))) unsigned int u32x2;
typedef __attribute__((ext_vector_type(4))) float f32x4;
typedef __attribute__((ext_vector_type(4))) unsigned int u32x4;
typedef __attribute__((ext_vector_type(8))) short s16x8;

#define B_  128
#define P_  196
#define E_  2048
#define D_  512
#define A_  512
#define M_  (B_*P_)   // 25088

// global_load_lds: 16B per lane, dest = wave-uniform base + lane*16
typedef __attribute__((address_space(1))) const unsigned int gu32;
typedef __attribute__((address_space(3))) unsigned int lu32;
__device__ __forceinline__ void gl_lds16(const void* g, void* l) {
  __builtin_amdgcn_global_load_lds((gu32*)g, (lu32*)l, 16, 0, 0);
}

#define WAIT_VM3() asm volatile("s_waitcnt vmcnt(3)" ::: "memory")
#define WAIT_VM0() asm volatile("s_waitcnt vmcnt(0)" ::: "memory")
#define WAIT_LGKM0() asm volatile("s_waitcnt lgkmcnt(0)" ::: "memory")

// ---------------------------------------------------------------------------
// Kernel W: transpose + rne-bf16 + PRE-SWIZZLED TILED store:
// WeTs[kt*16384 + ((a*32 + c8*8) ^ ((a&7)<<3)) + j] == exact 32KB LDS image
// of K-tile kt (a = n-row 0..511, c8 = (e&31)>>3, j = e&7).
// ---------------------------------------------------------------------------
__global__ void we_conv_kernel(const float* __restrict__ We,
                               unsigned short* __restrict__ WeTs) {
  __shared__ float tile[32][33];
  const int tx = threadIdx.x, ty = threadIdx.y;
  const int a0 = blockIdx.x * 32, e0 = blockIdx.y * 32;
  tile[ty][tx] = We[(e0 + ty) * A_ + a0 + tx];
  __syncthreads();
  const float v = tile[tx][ty];              // = We[e0+tx][a0+ty]
  const unsigned int u = __float_as_uint(v);
  const unsigned short r = (unsigned short)((u + 0x7fffu + ((u >> 16) & 1u)) >> 16);
  const int a = a0 + ty;                     // n-row 0..511
  const int kt = blockIdx.y;                 // e-tile
  const int c8 = tx >> 3, j = tx & 7;
  const int dest = ((a * 32 + c8 * 8) ^ ((a & 7) << 3)) + j;
  WeTs[kt * 16384 + dest] = r;
}

// ---------------------------------------------------------------------------
// Kernel A: att2pb[b][a] = decoder_hidden[b] @ Wd + bd[a] + be[a]  (fp32)
// ---------------------------------------------------------------------------
__global__ void att2_kernel(const float* __restrict__ h, const float* __restrict__ Wd,
                            const float* __restrict__ bd, const float* __restrict__ be,
                            float* __restrict__ att2pb) {
  const int b = blockIdx.x;
  const int t = threadIdx.x;  // 256
  __shared__ float hs[D_];
  hs[t] = h[b * D_ + t];
  hs[t + 256] = h[b * D_ + t + 256];
  __syncthreads();
  float a0 = 0.f, a1 = 0.f;
  for (int d = 0; d < D_; ++d) {
    const float hv = hs[d];
    a0 = fmaf(hv, Wd[d * A_ + t], a0);
    a1 = fmaf(hv, Wd[d * A_ + t + 256], a1);
  }
  att2pb[b * A_ + t] = a0 + bd[t] + be[t];
  att2pb[b * A_ + t + 256] = a1 + bd[t + 256] + be[t + 256];
}

// ---------------------------------------------------------------------------
__device__ inline unsigned pk2(float a, float b) {
  union { __hip_bfloat162 h; unsigned u; } cv;
  cv.h = __float22bfloat162_rn(make_float2(a, b));
  return cv.u;
}

// ---------------------------------------------------------------------------
// Kernel B v10 (A/A resubmit of the proven-best 130.2 config): 16 waves
// (1024 thr), wave tile 32x128 (4m x 4n), K=32, B ring-3 via gl_lds DMA
// (pre-swizzled 32KB images), A ring-3 via reg+cvt, depth-2 prefetch,
// counted vmcnt(3) + raw s_barrier; A cvt+write AFTER the MFMA cluster.
// ---------------------------------------------------------------------------
__launch_bounds__(1024, 4)
__global__ void score_kernel(const float* __restrict__ enc,
                             const unsigned short* __restrict__ WeTs,
                             const float* __restrict__ att2pb,
                             const float* __restrict__ Wf,
                             float* __restrict__ att_part) {
  __shared__ unsigned short Bh[3][512 * 32];   // 3 x 32 KB, swizzled image
  __shared__ unsigned short Ahs[3][128 * 32];  // 3 x  8 KB, swizzled image

  const int bid = blockIdx.x;               // 0..195
  const int m0 = bid * 128;

  const int t = threadIdx.x;                // 0..1023
  const int lane = t & 63, w = t >> 6;      // 16 waves
  const int wm = (w >> 2) * 32;             // 0 | 32 | 64 | 96
  const int wn = (w & 3) * 128;             // 0 | 128 | 256 | 384

  // A staging: row r = t>>3 (0..127), 4 f32 at chunk c4 = t&7 -> 8B LDS write
  const int ar = t >> 3, ac4 = t & 7;
  const float* aptr = enc + (size_t)(m0 + ar) * E_ + ac4 * 4;
  const int awz = (ar * 32 + ac4 * 4) ^ ((ar & 7) << 3);   // shorts, 8B-aligned

  // B DMA: 2 x 16B per thread (linear image copy)
  const int doff = t * 8;                   // shorts; chunk i at +i*8192

  // fragment read offsets
  const int q = lane >> 4, fr = lane & 15;
  const int fx = (fr & 7) << 3;
  int fa[2], fb[8];
#pragma unroll
  for (int i = 0; i < 2; ++i) fa[i] = ((wm + i * 16 + fr) * 32 + q * 8) ^ fx;
#pragma unroll
  for (int j = 0; j < 8; ++j) fb[j] = ((wn + j * 16 + fr) * 32 + q * 8) ^ fx;

  const f32x4 zero = {0.f, 0.f, 0.f, 0.f};
  f32x4 acc[2][8];
#pragma unroll
  for (int mi = 0; mi < 2; ++mi)
#pragma unroll
    for (int ni = 0; ni < 8; ++ni) acc[mi][ni] = zero;

  // rotating buffers: *_c = compute (tile t), *_1 = t+1, *_2 = DMA tgt (t+2)
  unsigned short *bAc = &Ahs[0][0], *bA1 = &Ahs[1][0], *bA2 = &Ahs[2][0];
  unsigned short *bBc = &Bh[0][0],  *bB1 = &Bh[1][0],  *bB2 = &Bh[2][0];

  f32x4 aC, aN;   // A regs: aC = tile t+1 (cvt at end of iter t), aN = t+2

  // ---- prologue: stage tiles 0 and 1 (order: A0, B0 x2, A1, B1 x2)
  {
    aC = *(const f32x4*)(aptr);                           // A(0)
    gl_lds16(WeTs + doff, bBc + doff);                    // B(0)
    gl_lds16(WeTs + 8192 + doff, bBc + 8192 + doff);
    aN = *(const f32x4*)(aptr + 32);                      // A(1)
    gl_lds16(WeTs + 16384 + doff, bB1 + doff);            // B(1)
    gl_lds16(WeTs + 16384 + 8192 + doff, bB1 + 8192 + doff);
    u32x2 av; av[0] = pk2(aC[0], aC[1]); av[1] = pk2(aC[2], aC[3]);
    *(u32x2*)(bAc + awz) = av;                            // A(0) -> LDS
    aC = aN;
    WAIT_VM3();     // retires B(0); leaves A(1)+B(1)x2 in flight
    WAIT_LGKM0();
    __builtin_amdgcn_s_barrier();
  }

  for (int it = 0; it < 62; ++it) {
    // 1) issue stage(t+2): 1 A-load + 2 B-DMAs  (3 VMEM ops this iter)
    const int kof = (it + 2) * 32;
    aN = *(const f32x4*)(aptr + kof);
    const unsigned short* sb = WeTs + (size_t)(it + 2) * 16384;
    gl_lds16(sb + doff, bB2 + doff);
    gl_lds16(sb + 8192 + doff, bB2 + 8192 + doff);

    // 2) compute buffer t (B in two halves of 4 frags: register pressure)
    s16x8 fah[2], fbh[4];
    fah[0] = *(const s16x8*)(bAc + fa[0]);
    fah[1] = *(const s16x8*)(bAc + fa[1]);
#pragma unroll
    for (int j = 0; j < 4; ++j) fbh[j] = *(const s16x8*)(bBc + fb[j]);
    __builtin_amdgcn_s_setprio(1);
#pragma unroll
    for (int mi = 0; mi < 2; ++mi)
#pragma unroll
      for (int ni = 0; ni < 4; ++ni)
        acc[mi][ni] = __builtin_amdgcn_mfma_f32_16x16x32_bf16(fah[mi], fbh[ni], acc[mi][ni], 0, 0, 0);
    __builtin_amdgcn_s_setprio(0);
#pragma unroll
    for (int j = 0; j < 4; ++j) fbh[j] = *(const s16x8*)(bBc + fb[4 + j]);
    __builtin_amdgcn_s_setprio(1);
#pragma unroll
    for (int mi = 0; mi < 2; ++mi)
#pragma unroll
      for (int ni = 0; ni < 4; ++ni)
        acc[mi][4 + ni] = __builtin_amdgcn_mfma_f32_16x16x32_bf16(fah[mi], fbh[ni], acc[mi][4 + ni], 0, 0, 0);
    __builtin_amdgcn_s_setprio(0);

    // 3) cvt + write A(t+1) (aC regs issued last iter; compiler-counted wait)
    {
      u32x2 av; av[0] = pk2(aC[0], aC[1]); av[1] = pk2(aC[2], aC[3]);
      *(u32x2*)(bA1 + awz) = av;
    }
    aC = aN;

    // 4) counted drain: this iter's 3 stay in flight; tile t+1 fully resident
    WAIT_VM3();
    WAIT_LGKM0();
    __builtin_amdgcn_s_barrier();

    // 5) rotate
    unsigned short* tmp;
    tmp = bAc; bAc = bA1; bA1 = bA2; bA2 = tmp;
    tmp = bBc; bBc = bB1; bB1 = bB2; bB2 = tmp;
  }

  // ---- it = 62: compute tile 62, cvt+write A(63), full drain
  {
    s16x8 fah[2], fbh[4];
    fah[0] = *(const s16x8*)(bAc + fa[0]);
    fah[1] = *(const s16x8*)(bAc + fa[1]);
#pragma unroll
    for (int j = 0; j < 4; ++j) fbh[j] = *(const s16x8*)(bBc + fb[j]);
#pragma unroll
    for (int mi = 0; mi < 2; ++mi)
#pragma unroll
      for (int ni = 0; ni < 4; ++ni)
        acc[mi][ni] = __builtin_amdgcn_mfma_f32_16x16x32_bf16(fah[mi], fbh[ni], acc[mi][ni], 0, 0, 0);
#pragma unroll
    for (int j = 0; j < 4; ++j) fbh[j] = *(const s16x8*)(bBc + fb[4 + j]);
#pragma unroll
    for (int mi = 0; mi < 2; ++mi)
#pragma unroll
      for (int ni = 0; ni < 4; ++ni)
        acc[mi][4 + ni] = __builtin_amdgcn_mfma_f32_16x16x32_bf16(fah[mi], fbh[ni], acc[mi][4 + ni], 0, 0, 0);
    u32x2 av; av[0] = pk2(aC[0], aC[1]); av[1] = pk2(aC[2], aC[3]);
    *(u32x2*)(bA1 + awz) = av;                            // A(63)
    WAIT_VM0();     // B(63) retired
    WAIT_LGKM0();
    __builtin_amdgcn_s_barrier();
  }

  // ---- it = 63: compute tile 63 from bA1/bB1
  {
    s16x8 fah[2], fbh[4];
    fah[0] = *(const s16x8*)(bA1 + fa[0]);
    fah[1] = *(const s16x8*)(bA1 + fa[1]);
#pragma unroll
    for (int j = 0; j < 4; ++j) fbh[j] = *(const s16x8*)(bB1 + fb[j]);
#pragma unroll
    for (int mi = 0; mi < 2; ++mi)
#pragma unroll
      for (int ni = 0; ni < 4; ++ni)
        acc[mi][ni] = __builtin_amdgcn_mfma_f32_16x16x32_bf16(fah[mi], fbh[ni], acc[mi][ni], 0, 0, 0);
#pragma unroll
    for (int j = 0; j < 4; ++j) fbh[j] = *(const s16x8*)(bB1 + fb[4 + j]);
#pragma unroll
    for (int mi = 0; mi < 2; ++mi)
#pragma unroll
      for (int ni = 0; ni < 4; ++ni)
        acc[mi][4 + ni] = __builtin_amdgcn_mfma_f32_16x16x32_bf16(fah[mi], fbh[ni], acc[mi][4 + ni], 0, 0, 0);
  }

  // epilogue: s = sum_col relu(acc + att2pb[b][col]) * Wf[col], 16-lane reduce
  // C/D layout: col = lane&15, row = (lane>>4)*4 + reg
  const int colL = wn + fr;
  float wfv[8];
#pragma unroll
  for (int ni = 0; ni < 8; ++ni) wfv[ni] = Wf[colL + ni * 16];
#pragma unroll
  for (int mi = 0; mi < 2; ++mi) {
    const int rowb = m0 + wm + mi * 16 + (q << 2);
#pragma unroll
    for (int r = 0; r < 4; ++r) {
      const int row = rowb + r;
      const int bb = row / P_;
      const float* a2 = att2pb + bb * A_ + colL;
      float s = 0.f;
#pragma unroll
      for (int ni = 0; ni < 8; ++ni)
        s += fmaxf(acc[mi][ni][r] + a2[ni * 16], 0.f) * wfv[ni];
#pragma unroll
      for (int off = 1; off < 16; off <<= 1) s += __shfl_xor(s, off);
      if (fr == 0) att_part[row * 4 + (w & 3)] = s;
    }
  }
}

// ---------------------------------------------------------------------------
// Kernel C: per (b, e-chunk): sum 4 partials -> softmax over P -> alpha,
// awe[b][e] = sum_p alpha[p] * enc[b][p][e].  grid = B*2, block 256.
// ---------------------------------------------------------------------------
__global__ void softmax_awe_kernel(const float* __restrict__ enc,
                                   const float* __restrict__ att_part,
                                   float* __restrict__ out) {
  const int bid = blockIdx.x;
  const int b = bid >> 1, ch = bid & 1;
  const int t = threadIdx.x;
  __shared__ float sm[256];
  __shared__ float alpha_s[P_];

  float av = -1e30f;
  if (t < P_) {
    const float* apt = att_part + (b * P_ + t) * 4;
    av = (apt[0] + apt[1]) + (apt[2] + apt[3]);
  }
  sm[t] = av;
  __syncthreads();
  for (int st = 128; st > 0; st >>= 1) {
    if (t < st) sm[t] = fmaxf(sm[t], sm[t + st]);
    __syncthreads();
  }
  const float mx = sm[0];
  __syncthreads();
  float ev = 0.f;
  if (t < P_) ev = __expf(av - mx);
  sm[t] = ev;
  __syncthreads();
  for (int st = 128; st > 0; st >>= 1) {
    if (t < st) sm[t] += sm[t + st];
    __syncthreads();
  }
  const float denom = sm[0];
  const float al = ev / denom;
  if (t < P_) {
    alpha_s[t] = al;
    if (ch == 0) out[B_ * E_ + b * P_ + t] = al;   // alpha output
  }
  __syncthreads();

  const int e0 = ch * 1024 + t * 4;
  const float* ebase = enc + (size_t)b * P_ * E_ + e0;
  f32x4 acc = {0.f, 0.f, 0.f, 0.f};
  for (int p = 0; p < P_; ++p) {
    const f32x4 v = *(const f32x4*)(ebase + (size_t)p * E_);
    const float a = alpha_s[p];
    acc.x += a * v.x; acc.y += a * v.y; acc.z += a * v.z; acc.w += a * v.w;
  }
  *(f32x4*)(out + b * E_ + e0) = acc;
}

// ---------------------------------------------------------------------------
extern "C" void kernel_launch(void* const* d_in, const int* in_sizes, int n_in,
                              void* d_out, int out_size, void* d_ws, size_t ws_size,
                              hipStream_t stream) {
  const float* enc = (const float*)d_in[0];
  const float* h   = (const float*)d_in[1];
  const float* We  = (const float*)d_in[2];
  const float* be  = (const float*)d_in[3];
  const float* Wd  = (const float*)d_in[4];
  const float* bd  = (const float*)d_in[5];
  const float* Wf  = (const float*)d_in[6];
  // d_in[7] = bf: constant shift before softmax -> cancels; unused.
  float* out = (float*)d_out;

  // workspace layout (~2.7 MB)
  float* att2pb = (float*)d_ws;                       // 128*512 f32
  float* att_part = att2pb + B_ * A_;                 // 25088*4 f32
  unsigned short* WeTs = (unsigned short*)(att_part + M_ * 4);  // 64*16384 u16

  we_conv_kernel<<<dim3(A_ / 32, E_ / 32), dim3(32, 32), 0, stream>>>(We, WeTs);
  att2_kernel<<<B_, 256, 0, stream>>>(h, Wd, bd, be, att2pb);
  score_kernel<<<M_ / 128, 1024, 0, stream>>>(enc, WeTs, att2pb, Wf, att_part);
  softmax_awe_kernel<<<B_ * 2, 256, 0, stream>>>(enc, att_part, out);
}